// Round 12
// baseline (167.188 us; speedup 1.0000x reference)
//
#include <hip/hip_runtime.h>

#define TSTEPS 32
#define HID 1024
#define NCLS 10
#define BATCH 8
#define GGRP 32            // groups = H / TSTEPS
#define MROWS 8192         // BATCH * 1024 rows of the big GEMM
#define GK 2048            // K dim (W)
#define GN 1024            // N dim (HIDDEN)
#define ABUF 8192          // shorts per A LDS buffer (hi 4096 + lo 4096)
#define CLDS 40            // conv LDS row pitch in shorts (80B, 16B aligned)

typedef __attribute__((ext_vector_type(8))) short bf16x8;
typedef __attribute__((ext_vector_type(16))) float f32x16;

__device__ __forceinline__ unsigned short bf16_rne(float v) {
    unsigned u = __builtin_bit_cast(unsigned, v);
    return (unsigned short)((u + 0x7FFFu + ((u >> 16) & 1u)) >> 16);
}
__device__ __forceinline__ float bf16_f(unsigned short h) {
    unsigned u = (unsigned)h << 16;
    return __builtin_bit_cast(float, u);
}
__device__ __forceinline__ void gload16(const unsigned short* g, unsigned short* l) {
    __builtin_amdgcn_global_load_lds(
        (const __attribute__((address_space(1))) void*)g,
        (__attribute__((address_space(3))) void*)l, 16, 0, 0);
}

// Tile format (A and B identical): tile = 128 rows x 32 k, 512 chunks of
// 8 bf16 (16B). chunk c: u=c>>6 (unit = rowband(u>>1, 32 rows) x khalf(u&1));
// w=c&63: row=(w&31), koct=(w>>5). Fragment = 64 consecutive chunks; lane l ->
// chunk (l&31)+32*(l>>5) -> contiguous 1KB: coalesced from GLOBAL (B path) or
// conflict-free ds_read_b128 from LDS (A path); gload_lds staging stays linear.

// ---------------- 1x1 conv -> packed bf16 hi/lo A tiles (LDS-staged) ----------------
__global__ __launch_bounds__(256) void conv_pack_kernel(
    const float4* __restrict__ x, const float* __restrict__ cw,
    const float* __restrict__ cb,
    unsigned short* __restrict__ Ahi, unsigned short* __restrict__ Alo)
{
    __shared__ __align__(16) unsigned short lh[128 * CLDS];
    __shared__ __align__(16) unsigned short ll[128 * CLDS];
    const int rb = blockIdx.x >> 6;     // 0..63 row-block
    const int kb = blockIdx.x & 63;     // 0..63 k-block
    const float c0 = cw[0], c1 = cw[1], c2 = cw[2], c3 = cw[3], cbv = cb[0];
    const int tid = threadIdx.x;

#pragma unroll
    for (int p = 0; p < 16; ++p) {
        int i = p * 256 + tid;          // 0..4095 over [128 rows][32 px]
        int row = i >> 5, px = i & 31;
        float4 a = x[(size_t)(rb * 128 + row) * 2048 + kb * 32 + px];
        float v = a.x * c0 + a.y * c1 + a.z * c2 + a.w * c3 + cbv;
        unsigned short h = bf16_rne(v);
        lh[row * CLDS + px] = h;
        ll[row * CLDS + px] = bf16_rne(v - bf16_f(h));
    }
    __syncthreads();

#pragma unroll
    for (int cc = 0; cc < 2; ++cc) {
        int c = tid + cc * 256;         // chunk 0..511
        int u = c >> 6, w = c & 63;
        int row = (u >> 1) * 32 + (w & 31);
        int ko  = (u & 1) * 2 + (w >> 5);   // k-octet 0..3
        bf16x8 h8 = *(const bf16x8*)(lh + row * CLDS + ko * 8);
        bf16x8 l8 = *(const bf16x8*)(ll + row * CLDS + ko * 8);
        size_t off = ((size_t)blockIdx.x * 512 + c) * 8;
        *(bf16x8*)(Ahi + off) = h8;
        *(bf16x8*)(Alo + off) = l8;
    }
}

// ---------------- w1 -> packed bf16 hi/lo B tiles (128-col tiles) ----------------
__global__ __launch_bounds__(256) void wpack_kernel(
    const float* __restrict__ wsrc, unsigned short* __restrict__ Bhi,
    unsigned short* __restrict__ Blo)
{
    const int kb  = blockIdx.x & 63;    // blockIdx.x = cbk*64 + kb
    const int cbk = blockIdx.x >> 6;    // 0..7 col-block
    const int tid = threadIdx.x;
#pragma unroll
    for (int cc = 0; cc < 2; ++cc) {
        int c = tid + cc * 256;         // chunk 0..511
        int u = c >> 6, w = c & 63;
        int row = (u >> 1) * 32 + (w & 31);
        int k0  = (u & 1) * 16 + (w >> 5) * 8;
        const float* pw = wsrc + ((size_t)(cbk * 128 + row) * 2048 + kb * 32 + k0);
        bf16x8 h8, l8;
#pragma unroll
        for (int e = 0; e < 8; ++e) {
            float v = pw[e];
            unsigned short h = bf16_rne(v);
            h8[e] = (short)h;
            l8[e] = (short)bf16_rne(v - bf16_f(h));
        }
        size_t off = ((size_t)blockIdx.x * 512 + c) * 8;
        *(bf16x8*)(Bhi + off) = h8;
        *(bf16x8*)(Blo + off) = l8;
    }
}

// ---------------- MFMA GEMM (3-term bf16 split, 32x32x16) + fused scan ----------------
// 128x128 tile, 4 waves (2x2 of 64x64), 256 threads.
// A: double-buffered LDS (2 x 16KB) via gload_lds (LDS pipe).
// B: direct global->VGPR coalesced frag loads, one K-step of flight (L2 pipe).
// Splits the per-CU byte load across LDS (48KB/blk-step) and L2 (48KB/blk-step)
// instead of pushing everything through LDS (R8: 176KB/CU-step, LDS-bound 5:1).
// iter KB: [vmcnt(VMC) drains A(KB) DMA only (B stays outstanding, FIFO);
// lgkm(0); barrier] -> stage A(KB+1) -> ds_read A(KB) frags -> MFMA tile KB-1
// -> load B(KB+2... = KB+1) into the just-freed B reg set.
// Swizzle wgid=bx*64+by -> xcd=by%8: A panel fetched once/XCD then L2-shared;
// B (16MB) L2-cached per XCD.
__global__ __launch_bounds__(256, 2) void gemm_scan_kernel(
    const unsigned short* __restrict__ Ahi, const unsigned short* __restrict__ Alo,
    const unsigned short* __restrict__ Bhi, const unsigned short* __restrict__ Blo,
    const float* __restrict__ bias,
    const float* __restrict__ beta1, const float* __restrict__ thr1,
    float* __restrict__ S)
{
    // [0, 16384) shorts: 2 A buffers (hi 4096 | lo 4096 each);
    // whole 64KB reused as [128][128] f32 by the scan epilogue.
    __shared__ __align__(16) unsigned short sm[32768];

    const int tid = threadIdx.x;
    const int lane = tid & 63, wv = tid >> 6;
    const int wr = wv >> 1, wc = wv & 1;          // wave quadrant (2x2 of 64x64)
    const int by = blockIdx.x & 63;               // A row-panel (XCD = by%8)
    const int bx = blockIdx.x >> 6;               // B col-panel 0..7

    const unsigned short* gAh = Ahi + (size_t)by * 262144;
    const unsigned short* gAl = Alo + (size_t)by * 262144;
    const int fo = ((lane & 31) + 32 * (lane >> 5)) * 8;   // frag lane offset (shorts)
    const unsigned short* pBh = Bhi + (size_t)bx * 262144 + fo;
    const unsigned short* pBl = Blo + (size_t)bx * 262144 + fo;

    f32x16 acc[2][2];
#pragma unroll
    for (int i = 0; i < 2; ++i)
#pragma unroll
        for (int j = 0; j < 2; ++j) acc[i][j] = (f32x16)0.f;

    // frag sets: [set][0..7]=A (i,kh,hi/lo), [set][8..15]=B (j,kh,hi/lo)
    bf16x8 fr[2][16];

#define STAGE_A(buf, kb_)                                                        \
    {                                                                            \
        unsigned short* dst = sm + (buf) * ABUF + tid * 8;                       \
        const size_t o = (size_t)(kb_) * 4096 + tid * 8;                         \
        gload16(gAh + o, dst);                                                   \
        gload16(gAh + o + 2048, dst + 2048);                                     \
        gload16(gAl + o, dst + 4096);                                            \
        gload16(gAl + o + 2048, dst + 6144);                                     \
    }

#define LOADB(s, kb_)                                                            \
    {                                                                            \
        const unsigned short* bh_ = pBh + (size_t)(kb_) * 4096;                  \
        const unsigned short* bl_ = pBl + (size_t)(kb_) * 4096;                  \
        _Pragma("unroll")                                                        \
        for (int j = 0; j < 2; ++j)                                              \
            _Pragma("unroll")                                                    \
            for (int kh = 0; kh < 2; ++kh) {                                     \
                int u = (wc * 2 + j) * 2 + kh;                                   \
                fr[s][8 + (j * 2 + kh) * 2 + 0] = *(const bf16x8*)(bh_ + u * 512); \
                fr[s][8 + (j * 2 + kh) * 2 + 1] = *(const bf16x8*)(bl_ + u * 512); \
            }                                                                    \
    }

#define READFA(s, bufp)                                                          \
    {                                                                            \
        const unsigned short* bp_ = (bufp);                                      \
        _Pragma("unroll")                                                        \
        for (int i = 0; i < 2; ++i)                                              \
            _Pragma("unroll")                                                    \
            for (int kh = 0; kh < 2; ++kh) {                                     \
                int ua = ((wr * 2 + i) * 2 + kh) * 512 + fo;                     \
                fr[s][(i * 2 + kh) * 2 + 0] = *(const bf16x8*)(bp_ + ua);        \
                fr[s][(i * 2 + kh) * 2 + 1] = *(const bf16x8*)(bp_ + 4096 + ua); \
            }                                                                    \
    }

#define MFMAF(s)                                                                 \
    {                                                                            \
        _Pragma("unroll")                                                        \
        for (int kh = 0; kh < 2; ++kh) {                                         \
            _Pragma("unroll")                                                    \
            for (int i = 0; i < 2; ++i)                                          \
                _Pragma("unroll")                                                \
                for (int j = 0; j < 2; ++j)                                      \
                    acc[i][j] = __builtin_amdgcn_mfma_f32_32x32x16_bf16(         \
                        fr[s][(i * 2 + kh) * 2], fr[s][8 + (j * 2 + kh) * 2],    \
                        acc[i][j], 0, 0, 0);                                     \
            _Pragma("unroll")                                                    \
            for (int i = 0; i < 2; ++i)                                          \
                _Pragma("unroll")                                                \
                for (int j = 0; j < 2; ++j)                                      \
                    acc[i][j] = __builtin_amdgcn_mfma_f32_32x32x16_bf16(         \
                        fr[s][(i * 2 + kh) * 2], fr[s][8 + (j * 2 + kh) * 2 + 1],\
                        acc[i][j], 0, 0, 0);                                     \
            _Pragma("unroll")                                                    \
            for (int i = 0; i < 2; ++i)                                          \
                _Pragma("unroll")                                                \
                for (int j = 0; j < 2; ++j)                                      \
                    acc[i][j] = __builtin_amdgcn_mfma_f32_32x32x16_bf16(         \
                        fr[s][(i * 2 + kh) * 2 + 1], fr[s][8 + (j * 2 + kh) * 2],\
                        acc[i][j], 0, 0, 0);                                     \
        }                                                                        \
    }

// KSTEP(SC, SN, KB, DOSTAGE, DOLOADB, VMC):
//   vmcnt(VMC): FIFO = [A(KB):4 oldest][B(KB):8] -> VMC=8 drains A(KB) only.
//   lgkm(0)+barrier: all waves' reads of buf[(KB+1)&1] (tile KB-1) done.
//   Then: stage A(KB+1) into that buffer; ds_read A(KB) frags -> set SN;
//   MFMA tile KB-1 from set SC; reload B(KB+1) into SC's B regs (freed).
#define KSTEP(SC, SN, KB, DOSTAGE, DOLOADB, VMC)                                 \
    {                                                                            \
        asm volatile("s_waitcnt vmcnt(" #VMC ")" ::: "memory");                  \
        asm volatile("s_waitcnt lgkmcnt(0)" ::: "memory");                       \
        __builtin_amdgcn_sched_barrier(0);                                       \
        __builtin_amdgcn_s_barrier();                                            \
        if (DOSTAGE) STAGE_A(((KB) + 1) & 1, (KB) + 1);                          \
        READFA(SN, sm + ((KB) & 1) * ABUF);                                      \
        MFMAF(SC);                                                               \
        if (DOLOADB) LOADB(SC, (KB) + 1);                                        \
    }

    // prologue: B(0)->set0, B(1)->set1, stage A(0),A(1); wait A(0); frags A(0)
    LOADB(0, 0);
    LOADB(1, 1);
    STAGE_A(0, 0);
    STAGE_A(1, 1);
    asm volatile("s_waitcnt vmcnt(4)" ::: "memory");   // B0,B1,A0 done; A1 flies
    __builtin_amdgcn_s_barrier();
    READFA(0, sm);

    KSTEP(0, 1, 1, 1, 1, 0);           // MFMA t0, read A1, stage A2, load B2
    KSTEP(1, 0, 2, 1, 1, 8);           // MFMA t1, read A2, stage A3, load B3
    for (int kb = 3; kb < 61; kb += 2) {
        KSTEP(0, 1, kb, 1, 1, 8);      // MFMA kb-1 (set0), read kb (set1)
        KSTEP(1, 0, kb + 1, 1, 1, 8);  // MFMA kb   (set1), read kb+1 (set0)
    }
    KSTEP(0, 1, 61, 1, 1, 8);          // MFMA 60, read 61, stage A62, load B62
    KSTEP(1, 0, 62, 1, 1, 8);          // MFMA 61, read 62, stage A63, load B63
    KSTEP(0, 1, 63, 0, 0, 8);          // MFMA 62, read 63 (vmcnt(8) drains A63)
    // epilogue: MFMA tile 63 (compiler waits for B63 reg loads)
    asm volatile("s_waitcnt lgkmcnt(0)" ::: "memory");
    __builtin_amdgcn_sched_barrier(0);
    MFMAF(1);
    __syncthreads();   // all waves done with LDS before scan epilogue reuses it

    // ---- fused leaky scan over t (reuse LDS as [128][128] f32, 64 KB) ----
    float* sb = (float*)sm;
    const float bclamp = fminf(fmaxf(beta1[0], 0.f), 1.f);
    const float th = thr1[0];

#pragma unroll
    for (int i = 0; i < 2; ++i)
#pragma unroll
        for (int j = 0; j < 2; ++j)
#pragma unroll
            for (int r = 0; r < 16; ++r) {
                int lr = wr * 64 + i * 32 + (r & 3) + 8 * (r >> 2) + 4 * (lane >> 5);
                int lc = wc * 64 + j * 32 + (lane & 31);
                sb[lr * 128 + lc] = acc[i][j][r];
            }
    __syncthreads();

    const int scol = tid & 127;        // 0..127
    const int half = tid >> 7;         // 0..1
    const float bv = bias[bx * 128 + scol];
#pragma unroll
    for (int p = 0; p < 2; ++p) {
        int gg = half * 2 + p;         // (b,g) group 0..3 within this row-panel
        float mem = 0.f, cnt = 0.f;
#pragma unroll
        for (int t = 0; t < TSTEPS; ++t) {
            float u = sb[(gg * 32 + t) * 128 + scol] + bv;
            mem = bclamp * mem + u;
            float spk = mem > th ? 1.f : 0.f;
            mem -= spk * th;
            cnt += spk;
        }
        S[(size_t)(by * 4 + gg) * GN + bx * 128 + scol] = cnt;
    }
}

// ---------------- FC2 ----------------
__global__ __launch_bounds__(256) void fc2_kernel(
    const float* __restrict__ s, const float* __restrict__ w2,
    const float* __restrict__ b2, float* __restrict__ h2)
{
    int bg  = blockIdx.x;     // 0..255
    int tid = threadIdx.x;
    const float* sp = s + (size_t)bg * HID;
    float part[NCLS];
#pragma unroll
    for (int c = 0; c < NCLS; ++c) part[c] = 0.f;
    for (int d = tid; d < HID; d += 256) {
        float sv = sp[d];
#pragma unroll
        for (int c = 0; c < NCLS; ++c) part[c] += sv * w2[c * HID + d];
    }
#pragma unroll
    for (int c = 0; c < NCLS; ++c)
        for (int off = 32; off > 0; off >>= 1)
            part[c] += __shfl_down(part[c], off, 64);
    __shared__ float red[NCLS][4];
    int wave = tid >> 6, lanei = tid & 63;
    if (lanei == 0)
#pragma unroll
        for (int c = 0; c < NCLS; ++c) red[c][wave] = part[c];
    __syncthreads();
    if (tid < NCLS) {
        float v = red[tid][0] + red[tid][1] + red[tid][2] + red[tid][3] + b2[tid];
        h2[bg * NCLS + tid] = v;
    }
}

// ---------------- scan over G + softmax ----------------
__global__ __launch_bounds__(128) void scan2_kernel(
    const float* __restrict__ h2, const float* __restrict__ beta2,
    const float* __restrict__ thr2, float* __restrict__ out)
{
    __shared__ float logits[BATCH][NCLS];
    int t = threadIdx.x;
    if (t < BATCH * NCLS) {
        int b = t / NCLS, c = t % NCLS;
        float bb = fminf(fmaxf(beta2[0], 0.f), 1.f);
        float th = thr2[0];
        float mem = 0.f, lg = 0.f;
        for (int g = 0; g < GGRP; ++g) {
            float u = h2[(b * GGRP + g) * NCLS + c];
            mem = bb * mem + u;
            float spk = mem > th ? 1.f : 0.f;
            mem -= spk * th;
            lg += spk;
        }
        logits[b][c] = lg;
    }
    __syncthreads();
    if (t < BATCH) {
        float mx = -1e30f;
        for (int c = 0; c < NCLS; ++c) mx = fmaxf(mx, logits[t][c]);
        float e[NCLS];
        float sum = 0.f;
        for (int c = 0; c < NCLS; ++c) { e[c] = expf(logits[t][c] - mx); sum += e[c]; }
        for (int c = 0; c < NCLS; ++c) out[t * NCLS + c] = e[c] / sum;
    }
}

extern "C" void kernel_launch(void* const* d_in, const int* in_sizes, int n_in,
                              void* d_out, int out_size, void* d_ws, size_t ws_size,
                              hipStream_t stream)
{
    const float* x     = (const float*)d_in[0];
    const float* cw    = (const float*)d_in[1];
    const float* cb    = (const float*)d_in[2];
    const float* w1    = (const float*)d_in[3];
    const float* b1    = (const float*)d_in[4];
    const float* beta1 = (const float*)d_in[5];
    const float* thr1  = (const float*)d_in[6];
    const float* w2    = (const float*)d_in[7];
    const float* b2    = (const float*)d_in[8];
    const float* beta2 = (const float*)d_in[9];
    const float* thr2  = (const float*)d_in[10];
    float* out = (float*)d_out;

    // ws: Ahi 32MB | Alo 32MB | Bhi 4MB | Blo 4MB | s 1MB | h2 10KB (~73MB)
    unsigned short* ahi = (unsigned short*)d_ws;
    unsigned short* alo = ahi + (size_t)MROWS * GK;
    unsigned short* bhi = alo + (size_t)MROWS * GK;
    unsigned short* blo = bhi + (size_t)GN * GK;
    float* s  = (float*)(blo + (size_t)GN * GK);
    float* h2 = s + (size_t)BATCH * GGRP * HID;

    conv_pack_kernel<<<4096, 256, 0, stream>>>((const float4*)x, cw, cb, ahi, alo);
    wpack_kernel    <<<512, 256, 0, stream>>>(w1, bhi, blo);
    gemm_scan_kernel<<<512, 256, 0, stream>>>(ahi, alo, bhi, blo, b1, beta1, thr1, s);
    fc2_kernel      <<<256, 256, 0, stream>>>(s, w2, b2, h2);
    scan2_kernel    <<<1, 128, 0, stream>>>(h2, beta2, thr2, out);
}

// Round 13
// 159.683 us; speedup vs baseline: 1.0470x; 1.0470x over previous
//
#include <hip/hip_runtime.h>

#define TSTEPS 32
#define HID 1024
#define NCLS 10
#define BATCH 8
#define GGRP 32            // groups = H / TSTEPS
#define MROWS 8192         // BATCH * 1024 rows of the big GEMM
#define GK 2048            // K dim (W)
#define GN 1024            // N dim (HIDDEN)
#define BUFSH 24576        // shorts per LDS buffer: Ahi 4K|Alo 4K|Bhi 8K|Blo 8K
#define CLDS 40            // conv LDS row pitch in shorts (80B, 16B aligned)

typedef __attribute__((ext_vector_type(8))) short bf16x8;
typedef __attribute__((ext_vector_type(16))) float f32x16;

__device__ __forceinline__ unsigned short bf16_rne(float v) {
    unsigned u = __builtin_bit_cast(unsigned, v);
    return (unsigned short)((u + 0x7FFFu + ((u >> 16) & 1u)) >> 16);
}
__device__ __forceinline__ float bf16_f(unsigned short h) {
    unsigned u = (unsigned)h << 16;
    return __builtin_bit_cast(float, u);
}
__device__ __forceinline__ void gload16(const unsigned short* g, unsigned short* l) {
    __builtin_amdgcn_global_load_lds(
        (const __attribute__((address_space(1))) void*)g,
        (__attribute__((address_space(3))) void*)l, 16, 0, 0);
}

// A tile = 128 rows x 32 k (512 chunks of 8 bf16), B tile = 256 rows x 32 k
// (1024 chunks). chunk c: u=c>>6 (unit = rowband(u>>1,32r) x khalf(u&1)),
// w=c&63: row=(w&31), koct=(w>>5). Fragment = 64 consecutive chunks; lane l ->
// chunk (l&31)+32*(l>>5): contiguous 1KB, conflict-free ds_read_b128, linear
// global_load_lds staging (m104 rule).

// ---------------- 1x1 conv -> packed bf16 hi/lo A tiles (LDS-staged) ----------------
__global__ __launch_bounds__(256) void conv_pack_kernel(
    const float4* __restrict__ x, const float* __restrict__ cw,
    const float* __restrict__ cb,
    unsigned short* __restrict__ Ahi, unsigned short* __restrict__ Alo)
{
    __shared__ __align__(16) unsigned short lh[128 * CLDS];
    __shared__ __align__(16) unsigned short ll[128 * CLDS];
    const int rb = blockIdx.x >> 6;     // 0..63 row-block
    const int kb = blockIdx.x & 63;     // 0..63 k-block
    const float c0 = cw[0], c1 = cw[1], c2 = cw[2], c3 = cw[3], cbv = cb[0];
    const int tid = threadIdx.x;

#pragma unroll
    for (int p = 0; p < 16; ++p) {
        int i = p * 256 + tid;          // 0..4095 over [128 rows][32 px]
        int row = i >> 5, px = i & 31;
        float4 a = x[(size_t)(rb * 128 + row) * 2048 + kb * 32 + px];
        float v = a.x * c0 + a.y * c1 + a.z * c2 + a.w * c3 + cbv;
        unsigned short h = bf16_rne(v);
        lh[row * CLDS + px] = h;
        ll[row * CLDS + px] = bf16_rne(v - bf16_f(h));
    }
    __syncthreads();

#pragma unroll
    for (int cc = 0; cc < 2; ++cc) {
        int c = tid + cc * 256;         // chunk 0..511
        int u = c >> 6, w = c & 63;
        int row = (u >> 1) * 32 + (w & 31);
        int ko  = (u & 1) * 2 + (w >> 5);   // k-octet 0..3
        bf16x8 h8 = *(const bf16x8*)(lh + row * CLDS + ko * 8);
        bf16x8 l8 = *(const bf16x8*)(ll + row * CLDS + ko * 8);
        size_t off = ((size_t)blockIdx.x * 512 + c) * 8;
        *(bf16x8*)(Ahi + off) = h8;
        *(bf16x8*)(Alo + off) = l8;
    }
}

// ---------------- w1 -> packed bf16 hi/lo B tiles (256-col tiles) ----------------
__global__ __launch_bounds__(256) void wpack_kernel(
    const float* __restrict__ wsrc, unsigned short* __restrict__ Bhi,
    unsigned short* __restrict__ Blo)
{
    const int kb  = blockIdx.x & 63;    // blockIdx.x = cbk*64 + kb
    const int cbk = blockIdx.x >> 6;    // 0..3 col-block
    const int tid = threadIdx.x;
#pragma unroll
    for (int cc = 0; cc < 4; ++cc) {
        int c = tid + cc * 256;         // chunk 0..1023
        int u = c >> 6, w = c & 63;
        int col = cbk * 256 + (u >> 1) * 32 + (w & 31);
        int k0  = kb * 32 + (u & 1) * 16 + (w >> 5) * 8;
        const float* pw = wsrc + ((size_t)col * 2048 + k0);
        bf16x8 h8, l8;
#pragma unroll
        for (int e = 0; e < 8; ++e) {
            float v = pw[e];
            unsigned short h = bf16_rne(v);
            h8[e] = (short)h;
            l8[e] = (short)bf16_rne(v - bf16_f(h));
        }
        size_t off = ((size_t)blockIdx.x * 1024 + c) * 8;
        *(bf16x8*)(Bhi + off) = h8;
        *(bf16x8*)(Blo + off) = l8;
    }
}

// ---------------- MFMA GEMM (3-term bf16 split, 32x32x16) + fused scan ----------------
// 128x256 tile, BK=32, 8 waves (2x4 of 64x64), 512 threads, 3 LDS buffers.
// m201-style 2-PHASE-PER-K-TILE schedule (T3+T4+T5): each phase =
//   { 8 ds_reads (this phase's kh frags) ; 3 staging gloads ;
//     [vmcnt(6) at kh1 only -- counted, never 0 in steady state] ;
//     s_barrier ; lgkmcnt(0) ; sched_barrier(0) ;
//     setprio(1) ; 12 MFMA ; setprio(0) ; s_barrier }
// Buffer lifetime: STAGE(KB+2) lands in buf (KB+2)%3 = buf of tile KB-1,
// fully read by all waves before KB-1's kh1 end-barrier (lgkm0-guarded).
// vmcnt(6) at kh1 of KB drains tile KB+1's 6 loads (KB+2's 6 remain) ->
// buf (KB+1)%3 globally visible after the phase-end barrier.
__global__ __launch_bounds__(512) void gemm_scan_kernel(
    const unsigned short* __restrict__ Ahi, const unsigned short* __restrict__ Alo,
    const unsigned short* __restrict__ Bhi, const unsigned short* __restrict__ Blo,
    const float* __restrict__ bias,
    const float* __restrict__ beta1, const float* __restrict__ thr1,
    float* __restrict__ S)
{
    // per buffer (shorts): Ahi[0,4096) Alo[4096,8192) Bhi[8192,16384) Blo[16384,24576)
    __shared__ __align__(16) unsigned short sm[3 * BUFSH];   // 147,456 B

    const int tid = threadIdx.x;
    const int lane = tid & 63, wv = tid >> 6;
    const int wr = wv >> 2, wc = wv & 3;          // wave quadrant (2x4 of 64x64)
    const int by = blockIdx.x & 63;               // A row-panel (XCD = by%8)
    const int bx = blockIdx.x >> 6;               // B col-panel 0..3

    const unsigned short* gAh = Ahi + (size_t)by * 262144;
    const unsigned short* gAl = Alo + (size_t)by * 262144;
    const unsigned short* gBh = Bhi + (size_t)bx * 524288;
    const unsigned short* gBl = Blo + (size_t)bx * 524288;

    f32x16 acc[2][2];
#pragma unroll
    for (int i = 0; i < 2; ++i)
#pragma unroll
        for (int j = 0; j < 2; ++j) acc[i][j] = (f32x16)0.f;

    // per-phase frags: [0..3]=A (i,hi/lo), [4..7]=B (j,hi/lo)
    bf16x8 fr[8];
    const int fo = ((lane & 31) + 32 * (lane >> 5)) * 8;

#define STAGE_H(buf, kb_, half)                                                  \
    {                                                                            \
        unsigned short* dst = sm + (buf) * BUFSH;                                \
        const size_t ao = (size_t)(kb_) * 4096 + tid * 8;                        \
        const size_t bo = (size_t)(kb_) * 8192 + tid * 8;                        \
        if ((half) == 0) {                                                       \
            gload16(gAh + ao, dst + tid * 8);                                    \
            gload16(gAl + ao, dst + 4096 + tid * 8);                             \
            gload16(gBh + bo, dst + 8192 + tid * 8);                             \
        } else {                                                                 \
            gload16(gBh + bo + 4096, dst + 12288 + tid * 8);                     \
            gload16(gBl + bo, dst + 16384 + tid * 8);                            \
            gload16(gBl + bo + 4096, dst + 20480 + tid * 8);                     \
        }                                                                        \
    }

#define MFMA12()                                                                 \
    {                                                                            \
        _Pragma("unroll")                                                        \
        for (int i = 0; i < 2; ++i)                                              \
            _Pragma("unroll")                                                    \
            for (int j = 0; j < 2; ++j)                                          \
                acc[i][j] = __builtin_amdgcn_mfma_f32_32x32x16_bf16(             \
                    fr[i * 2 + 0], fr[4 + j * 2 + 0], acc[i][j], 0, 0, 0);       \
        _Pragma("unroll")                                                        \
        for (int i = 0; i < 2; ++i)                                              \
            _Pragma("unroll")                                                    \
            for (int j = 0; j < 2; ++j)                                          \
                acc[i][j] = __builtin_amdgcn_mfma_f32_32x32x16_bf16(             \
                    fr[i * 2 + 0], fr[4 + j * 2 + 1], acc[i][j], 0, 0, 0);       \
        _Pragma("unroll")                                                        \
        for (int i = 0; i < 2; ++i)                                              \
            _Pragma("unroll")                                                    \
            for (int j = 0; j < 2; ++j)                                          \
                acc[i][j] = __builtin_amdgcn_mfma_f32_32x32x16_bf16(             \
                    fr[i * 2 + 1], fr[4 + j * 2 + 0], acc[i][j], 0, 0, 0);       \
    }

// PHASE(bufp, KH, DOSTAGE, SBUF, SKB, HALF, DOVM, VMC)
#define PHASE(bufp, KH, DOSTAGE, SBUF, SKB, HALF, DOVM, VMC)                     \
    {                                                                            \
        const unsigned short* bp_ = (bufp);                                      \
        _Pragma("unroll")                                                        \
        for (int i = 0; i < 2; ++i) {                                            \
            int ua = (((wr * 2 + i) * 2 + (KH)) << 9) + fo;                      \
            fr[i * 2 + 0] = *(const bf16x8*)(bp_ + ua);                          \
            fr[i * 2 + 1] = *(const bf16x8*)(bp_ + 4096 + ua);                   \
        }                                                                        \
        _Pragma("unroll")                                                        \
        for (int j = 0; j < 2; ++j) {                                            \
            int ub = (((wc * 2 + j) * 2 + (KH)) << 9) + fo;                      \
            fr[4 + j * 2 + 0] = *(const bf16x8*)(bp_ + 8192 + ub);               \
            fr[4 + j * 2 + 1] = *(const bf16x8*)(bp_ + 16384 + ub);              \
        }                                                                        \
        if (DOSTAGE) STAGE_H(SBUF, SKB, HALF);                                   \
        if (DOVM) asm volatile("s_waitcnt vmcnt(" #VMC ")" ::: "memory");        \
        __builtin_amdgcn_s_barrier();                                            \
        asm volatile("s_waitcnt lgkmcnt(0)" ::: "memory");                       \
        __builtin_amdgcn_sched_barrier(0);                                       \
        __builtin_amdgcn_s_setprio(1);                                           \
        MFMA12();                                                                \
        __builtin_amdgcn_s_setprio(0);                                           \
        __builtin_amdgcn_s_barrier();                                            \
    }

    // prologue: stage tiles 0,1,2 fully (18 gloads/wave); tile 0 visible
    STAGE_H(0, 0, 0); STAGE_H(0, 0, 1);
    STAGE_H(1, 1, 0); STAGE_H(1, 1, 1);
    STAGE_H(2, 2, 0); STAGE_H(2, 2, 1);
    asm volatile("s_waitcnt vmcnt(12)" ::: "memory");
    __builtin_amdgcn_s_barrier();

    // tile 0 (no staging; vmcnt(6) at kh1 drains tile 1)
    PHASE(sm, 0, 0, 0, 0, 0, 0, 0);
    PHASE(sm, 1, 0, 0, 0, 0, 1, 6);

    // tiles 1..61: stage tile kb+2 (half 0 at kh0, half 1 at kh1); vmcnt(6) at kh1
    int cur = 1;                       // kb % 3
    for (int kb = 1; kb <= 61; ++kb) {
        const unsigned short* bp = sm + cur * BUFSH;
        int stg = (cur == 0) ? 2 : cur - 1;   // (kb+2) % 3
        PHASE(bp, 0, 1, stg, kb + 2, 0, 0, 0);
        PHASE(bp, 1, 1, stg, kb + 2, 1, 1, 6);
        cur = (cur == 2) ? 0 : cur + 1;
    }
    // tile 62 (kb%3 = 2): no staging; vmcnt(0) at kh1 -> tile 63 visible
    PHASE(sm + 2 * BUFSH, 0, 0, 0, 0, 0, 0, 0);
    PHASE(sm + 2 * BUFSH, 1, 0, 0, 0, 0, 1, 0);
    // tile 63 (kb%3 = 0)
    PHASE(sm, 0, 0, 0, 0, 0, 0, 0);
    PHASE(sm, 1, 0, 0, 0, 0, 0, 0);

    __syncthreads();   // all waves done with LDS before scan epilogue reuses it

    // ---- fused leaky scan over t (reuse LDS as [64][256] f32 buffer, 64 KB) ----
    float* sb = (float*)sm;
    const float bclamp = fminf(fmaxf(beta1[0], 0.f), 1.f);
    const float th = thr1[0];
    const int sbg = tid >> 8;          // 0..1 ((b,g) group within band)
    const int scol = tid & 255;        // 0..255
    const float bv = bias[bx * 256 + scol];

#pragma unroll
    for (int band = 0; band < 2; ++band) {
        if (wr == band) {
#pragma unroll
            for (int i = 0; i < 2; ++i)
#pragma unroll
                for (int j = 0; j < 2; ++j)
#pragma unroll
                    for (int r = 0; r < 16; ++r) {
                        int lr = i * 32 + (r & 3) + 8 * (r >> 2) + 4 * (lane >> 5);
                        int lc = wc * 64 + j * 32 + (lane & 31);
                        sb[lr * 256 + lc] = acc[i][j][r];
                    }
        }
        __syncthreads();
        float mem = 0.f, cnt = 0.f;
#pragma unroll
        for (int t = 0; t < TSTEPS; ++t) {
            float u = sb[(sbg * 32 + t) * 256 + scol] + bv;
            mem = bclamp * mem + u;
            float spk = mem > th ? 1.f : 0.f;
            mem -= spk * th;
            cnt += spk;
        }
        int bgg = by * 4 + band * 2 + sbg;
        S[(size_t)bgg * GN + bx * 256 + scol] = cnt;
        __syncthreads();
    }
}

// ---------------- FC2 ----------------
__global__ __launch_bounds__(256) void fc2_kernel(
    const float* __restrict__ s, const float* __restrict__ w2,
    const float* __restrict__ b2, float* __restrict__ h2)
{
    int bg  = blockIdx.x;     // 0..255
    int tid = threadIdx.x;
    const float* sp = s + (size_t)bg * HID;
    float part[NCLS];
#pragma unroll
    for (int c = 0; c < NCLS; ++c) part[c] = 0.f;
    for (int d = tid; d < HID; d += 256) {
        float sv = sp[d];
#pragma unroll
        for (int c = 0; c < NCLS; ++c) part[c] += sv * w2[c * HID + d];
    }
#pragma unroll
    for (int c = 0; c < NCLS; ++c)
        for (int off = 32; off > 0; off >>= 1)
            part[c] += __shfl_down(part[c], off, 64);
    __shared__ float red[NCLS][4];
    int wave = tid >> 6, lanei = tid & 63;
    if (lanei == 0)
#pragma unroll
        for (int c = 0; c < NCLS; ++c) red[c][wave] = part[c];
    __syncthreads();
    if (tid < NCLS) {
        float v = red[tid][0] + red[tid][1] + red[tid][2] + red[tid][3] + b2[tid];
        h2[bg * NCLS + tid] = v;
    }
}

// ---------------- scan over G + softmax ----------------
__global__ __launch_bounds__(128) void scan2_kernel(
    const float* __restrict__ h2, const float* __restrict__ beta2,
    const float* __restrict__ thr2, float* __restrict__ out)
{
    __shared__ float logits[BATCH][NCLS];
    int t = threadIdx.x;
    if (t < BATCH * NCLS) {
        int b = t / NCLS, c = t % NCLS;
        float bb = fminf(fmaxf(beta2[0], 0.f), 1.f);
        float th = thr2[0];
        float mem = 0.f, lg = 0.f;
        for (int g = 0; g < GGRP; ++g) {
            float u = h2[(b * GGRP + g) * NCLS + c];
            mem = bb * mem + u;
            float spk = mem > th ? 1.f : 0.f;
            mem -= spk * th;
            lg += spk;
        }
        logits[b][c] = lg;
    }
    __syncthreads();
    if (t < BATCH) {
        float mx = -1e30f;
        for (int c = 0; c < NCLS; ++c) mx = fmaxf(mx, logits[t][c]);
        float e[NCLS];
        float sum = 0.f;
        for (int c = 0; c < NCLS; ++c) { e[c] = expf(logits[t][c] - mx); sum += e[c]; }
        for (int c = 0; c < NCLS; ++c) out[t * NCLS + c] = e[c] / sum;
    }
}

extern "C" void kernel_launch(void* const* d_in, const int* in_sizes, int n_in,
                              void* d_out, int out_size, void* d_ws, size_t ws_size,
                              hipStream_t stream)
{
    const float* x     = (const float*)d_in[0];
    const float* cw    = (const float*)d_in[1];
    const float* cb    = (const float*)d_in[2];
    const float* w1    = (const float*)d_in[3];
    const float* b1    = (const float*)d_in[4];
    const float* beta1 = (const float*)d_in[5];
    const float* thr1  = (const float*)d_in[6];
    const float* w2    = (const float*)d_in[7];
    const float* b2    = (const float*)d_in[8];
    const float* beta2 = (const float*)d_in[9];
    const float* thr2  = (const float*)d_in[10];
    float* out = (float*)d_out;

    // ws: Ahi 32MB | Alo 32MB | Bhi 4MB | Blo 4MB | s 1MB | h2 10KB (~73MB)
    unsigned short* ahi = (unsigned short*)d_ws;
    unsigned short* alo = ahi + (size_t)MROWS * GK;
    unsigned short* bhi = alo + (size_t)MROWS * GK;
    unsigned short* blo = bhi + (size_t)GN * GK;
    float* s  = (float*)(blo + (size_t)GN * GK);
    float* h2 = s + (size_t)BATCH * GGRP * HID;

    conv_pack_kernel<<<4096, 256, 0, stream>>>((const float4*)x, cw, cb, ahi, alo);
    wpack_kernel    <<<256, 256, 0, stream>>>(w1, bhi, blo);
    gemm_scan_kernel<<<256, 512, 0, stream>>>(ahi, alo, bhi, blo, b1, beta1, thr1, s);
    fc2_kernel      <<<256, 256, 0, stream>>>(s, w2, b2, h2);
    scan2_kernel    <<<1, 128, 0, stream>>>(h2, beta2, thr2, out);
}